// Round 2
// baseline (7277.992 us; speedup 1.0000x reference)
//
#include <hip/hip_runtime.h>

// Encoder: point MLP (4->64->128->256->256) + segment-mean pool + latent MLP.
// fp32, conservative structure: 32 pts/block, acts in LDS [k][pt], weights
// read directly from global (L1-broadcast), no intra-layer barriers.
// Sums buffer: d_ws if large enough, else second half of d_out (log_var
// region, each latent block reads its sums before overwriting).

#define NB   4096
#define NTOT 1048576
#define PTS  32
#define OUT_HALF (NB * 256)   // 1048576

__device__ __forceinline__ float lrelu(float x){ return x > 0.0f ? x : 0.01f * x; }

__device__ __forceinline__ int find_cloud(const int* __restrict__ idx, int j){
  // searchsorted(idx, j, side="right")
  int lo = 0, hi = NB;
  while (lo < hi){
    int mid = (lo + hi) >> 1;
    if (idx[mid] <= j) lo = mid + 1; else hi = mid;
  }
  return lo;
}

// One layer K -> M over 32 points. Thread (pq=t&7, mg=t>>3) owns points
// p0=pq*4..+3 and output dims m0=mg*MT..+MT-1. Weights row-major [M][K]
// read as float4 along K from global. No barriers inside.
template<int K, int M, int MT, bool RELU, bool WRITE>
__device__ __forceinline__ void layer(
    const float (*__restrict__ aIn)[PTS], float (*__restrict__ aOut)[PTS],
    const float* __restrict__ W, const float* __restrict__ Bv,
    int p0, int m0, float* __restrict__ accOut)
{
  float acc[4][MT];
  #pragma unroll
  for (int j = 0; j < MT; ++j){
    const float bv = Bv[m0 + j];
    #pragma unroll
    for (int p = 0; p < 4; ++p) acc[p][j] = bv;
  }
  #pragma unroll 2
  for (int k4 = 0; k4 < K / 4; ++k4){
    const float4 a0 = *reinterpret_cast<const float4*>(&aIn[k4*4 + 0][p0]);
    const float4 a1 = *reinterpret_cast<const float4*>(&aIn[k4*4 + 1][p0]);
    const float4 a2 = *reinterpret_cast<const float4*>(&aIn[k4*4 + 2][p0]);
    const float4 a3 = *reinterpret_cast<const float4*>(&aIn[k4*4 + 3][p0]);
    const float pa[4][4] = {
      {a0.x, a1.x, a2.x, a3.x}, {a0.y, a1.y, a2.y, a3.y},
      {a0.z, a1.z, a2.z, a3.z}, {a0.w, a1.w, a2.w, a3.w}};
    #pragma unroll
    for (int j = 0; j < MT; ++j){
      const float4 w = *reinterpret_cast<const float4*>(&W[(size_t)(m0 + j) * K + k4 * 4]);
      #pragma unroll
      for (int p = 0; p < 4; ++p)
        acc[p][j] += pa[p][0] * w.x + pa[p][1] * w.y + pa[p][2] * w.z + pa[p][3] * w.w;
    }
  }
  if constexpr (WRITE){
    #pragma unroll
    for (int j = 0; j < MT; ++j)
      #pragma unroll
      for (int p = 0; p < 4; ++p)
        aOut[m0 + j][p0 + p] = RELU ? lrelu(acc[p][j]) : acc[p][j];
  } else {
    #pragma unroll
    for (int j = 0; j < MT; ++j)
      #pragma unroll
      for (int p = 0; p < 4; ++p)
        accOut[p * MT + j] = acc[p][j];
  }
}

__global__ __launch_bounds__(256, 2)
void point_mlp_kernel(const float* __restrict__ points, const int* __restrict__ idx,
    const float* __restrict__ w0, const float* __restrict__ b0,
    const float* __restrict__ w1, const float* __restrict__ b1,
    const float* __restrict__ w2, const float* __restrict__ b2,
    const float* __restrict__ w3, const float* __restrict__ b3,
    float* __restrict__ sums)
{
  __shared__ float s_pts[4][PTS];
  __shared__ float s_h1[64][PTS];
  __shared__ float s_h2[128][PTS];
  __shared__ float s_h3[256][PTS];

  const int t    = threadIdx.x;
  const int base = blockIdx.x * PTS;
  const int pq   = t & 7;
  const int mg   = t >> 3;      // 0..31
  const int p0   = pq * 4;

  if (t < PTS){
    const float4 v = *reinterpret_cast<const float4*>(points + (size_t)(base + t) * 4);
    s_pts[0][t] = v.x; s_pts[1][t] = v.y; s_pts[2][t] = v.z; s_pts[3][t] = v.w;
  }
  __syncthreads();

  // L0: 4 -> 64, 2 dims per thread
  #pragma unroll
  for (int j = 0; j < 2; ++j){
    const int m = mg * 2 + j;
    const float4 wv = *reinterpret_cast<const float4*>(w0 + m * 4);
    const float bv = b0[m];
    #pragma unroll
    for (int p = 0; p < 4; ++p){
      const float s = bv + s_pts[0][p0+p]*wv.x + s_pts[1][p0+p]*wv.y
                         + s_pts[2][p0+p]*wv.z + s_pts[3][p0+p]*wv.w;
      s_h1[m][p0 + p] = lrelu(s);
    }
  }
  __syncthreads();

  layer< 64, 128, 4, true, true >(s_h1, s_h2, w1, b1, p0, mg * 4, nullptr);
  __syncthreads();
  layer<128, 256, 8, true, true >(s_h2, s_h3, w2, b2, p0, mg * 8, nullptr);
  __syncthreads();
  float accL3[32];
  layer<256, 256, 8, false, false>(s_h3, nullptr, w3, b3, p0, mg * 8, accL3);

  // segment reduction: v[j] = sum over this thread's 4 points
  float v[8];
  #pragma unroll
  for (int j = 0; j < 8; ++j)
    v[j] = accL3[0*8+j] + accL3[1*8+j] + accL3[2*8+j] + accL3[3*8+j];

  const int cFirst = find_cloud(idx, base);
  const int cLast  = find_cloud(idx, base + PTS - 1);
  if (cFirst == cLast){
    #pragma unroll
    for (int off = 1; off < 8; off <<= 1)
      #pragma unroll
      for (int j = 0; j < 8; ++j)
        v[j] += __shfl_xor(v[j], off, 64);
    if (pq == 0){
      float* dst = sums + (size_t)cFirst * 256 + mg * 8;
      #pragma unroll
      for (int j = 0; j < 8; ++j) atomicAdd(dst + j, v[j]);
    }
  } else {
    // block straddles clouds (not hit with uniform 256-pt clouds; kept for correctness)
    #pragma unroll
    for (int p = 0; p < 4; ++p){
      const int c = find_cloud(idx, base + p0 + p);
      #pragma unroll
      for (int j = 0; j < 8; ++j)
        atomicAdd(sums + (size_t)c * 256 + mg * 8 + j, accL3[p * 8 + j]);
    }
  }
}

// ---- latent MLP: 4 clouds per block, 256 threads (thread = output dim) ----
__device__ __forceinline__ void lat_accum(const float (*__restrict__ in)[256],
    const float* __restrict__ W, const float* __restrict__ bias, int t, float acc[4])
{
  const float bv = bias[t];
  #pragma unroll
  for (int cl = 0; cl < 4; ++cl) acc[cl] = bv;
  const float4* __restrict__ wrow = reinterpret_cast<const float4*>(W + (size_t)t * 256);
  #pragma unroll 4
  for (int k4 = 0; k4 < 64; ++k4){
    const float4 w = wrow[k4];
    #pragma unroll
    for (int cl = 0; cl < 4; ++cl){
      const float4 a = *reinterpret_cast<const float4*>(&in[cl][k4 * 4]);
      acc[cl] += a.x * w.x + a.y * w.y + a.z * w.z + a.w * w.w;
    }
  }
}

__global__ __launch_bounds__(256)
void latent_kernel(const float* __restrict__ sums, const int* __restrict__ idx,
    const float* __restrict__ lw0, const float* __restrict__ lb0,
    const float* __restrict__ lw1, const float* __restrict__ lb1,
    const float* __restrict__ mw, const float* __restrict__ mb,
    const float* __restrict__ vw, const float* __restrict__ vb,
    float* __restrict__ out)
{
  __shared__ float s_in[4][256];
  __shared__ float s_a[4][256];
  const int t  = threadIdx.x;
  const int c0 = blockIdx.x * 4;

  #pragma unroll
  for (int cl = 0; cl < 4; ++cl){
    const int c = c0 + cl;
    const int cnt = idx[c] - (c ? idx[c - 1] : 0);
    s_in[cl][t] = sums[(size_t)c * 256 + t] / (float)cnt;   // per-cloud mean
  }
  __syncthreads();

  float acc[4];
  lat_accum(s_in, lw0, lb0, t, acc);
  #pragma unroll
  for (int cl = 0; cl < 4; ++cl) s_a[cl][t] = lrelu(acc[cl]);
  __syncthreads();

  lat_accum(s_a, lw1, lb1, t, acc);
  __syncthreads();                 // layer-0 reads of s_in long done; safe to reuse
  #pragma unroll
  for (int cl = 0; cl < 4; ++cl) s_in[cl][t] = lrelu(acc[cl]);
  __syncthreads();

  float accm[4], accv[4];
  lat_accum(s_in, mw, mb, t, accm);
  lat_accum(s_in, vw, vb, t, accv);
  #pragma unroll
  for (int cl = 0; cl < 4; ++cl){
    out[(size_t)(c0 + cl) * 256 + t]                    = accm[cl];  // mu
    out[(size_t)OUT_HALF + (size_t)(c0 + cl) * 256 + t] = accv[cl];  // log_var
  }
}

extern "C" void kernel_launch(void* const* d_in, const int* in_sizes, int n_in,
                              void* d_out, int out_size, void* d_ws, size_t ws_size,
                              hipStream_t stream) {
  const float* points = (const float*)d_in[0];
  const int*   idx    = (const int*)  d_in[1];
  const float* pw0 = (const float*)d_in[2],  *pb0 = (const float*)d_in[3];
  const float* pw1 = (const float*)d_in[4],  *pb1 = (const float*)d_in[5];
  const float* pw2 = (const float*)d_in[6],  *pb2 = (const float*)d_in[7];
  const float* pw3 = (const float*)d_in[8],  *pb3 = (const float*)d_in[9];
  const float* lw0 = (const float*)d_in[10], *lb0 = (const float*)d_in[11];
  const float* lw1 = (const float*)d_in[12], *lb1 = (const float*)d_in[13];
  const float* mw  = (const float*)d_in[14], *mb  = (const float*)d_in[15];
  const float* vw  = (const float*)d_in[16], *vb  = (const float*)d_in[17];
  float* out  = (float*)d_out;

  const size_t sums_bytes = (size_t)NB * 256 * sizeof(float);
  float* sums = (ws_size >= sums_bytes) ? (float*)d_ws : (out + OUT_HALF);

  hipMemsetAsync(sums, 0, sums_bytes, stream);
  point_mlp_kernel<<<NTOT / PTS, 256, 0, stream>>>(points, idx,
      pw0, pb0, pw1, pb1, pw2, pb2, pw3, pb3, sums);
  latent_kernel<<<NB / 4, 256, 0, stream>>>(sums, idx,
      lw0, lb0, lw1, lb1, mw, mb, vw, vb, out);
}

// Round 4
// 1166.211 us; speedup vs baseline: 6.2407x; 6.2407x over previous
//
#include <hip/hip_runtime.h>

// Encoder: point MLP (4->64->128->256->256) via split-bf16 MFMA + segment-mean
// pool + fp32 latent MLP.
// Round-4 de-risk: every kernel's static LDS <= 64 KB (PTS=64 -> 59 KB),
// smaller unroll bodies (max 256 MFMA/layer), scratch prefers d_ws.
// - Weights pre-split hi/lo bf16 (2 MFMAs per product), fragment-major.
// - A and B fragments use the SAME (lane,e)->k map, so k-order cancels.
// - C/D layout: col=lane&15, row=(lane>>4)*4+reg (HW-verified m89).

#define NB    4096
#define NTOT  1048576
#define PTS   64
#define OUT_HALF (NB * 256)       // 1048576 floats
#define WSPLIT_ELEMS 106496       // 8192 + 32768 + 65536 fragments-elems per array

typedef __attribute__((ext_vector_type(8))) short short8;
typedef __attribute__((ext_vector_type(4))) float f32x4;
typedef unsigned short u16;
typedef unsigned int   u32;

__device__ __forceinline__ float lrelu(float x){ return x > 0.0f ? x : 0.01f * x; }

__device__ __forceinline__ u16 f2bf(float x){            // round-to-nearest-even
  union{float f; u32 u;} v; v.f = x;
  u32 r = v.u + 0x7fffu + ((v.u >> 16) & 1u);
  return (u16)(r >> 16);
}
__device__ __forceinline__ float bf2f(u16 h){
  union{u32 u; float f;} v; v.u = ((u32)h) << 16; return v.f;
}

__device__ __forceinline__ int find_cloud(const int* __restrict__ idx, int j){
  int lo = 0, hi = NB;
  while (lo < hi){
    int mid = (lo + hi) >> 1;
    if (idx[mid] <= j) lo = mid + 1; else hi = mid;
  }
  return lo;
}

// ---- prologue: split W into hi/lo bf16, fragment-major ---------------------
// frag = 512 elems: [lane 0..63][e 0..7]; elem (lane,e) = W[mtg*16+(lane&15)]
// [ks*32+(lane>>4)*8+e]. Layer offsets (u16 elems): L1=0, L2=8192, L3=40960.
__global__ void wsplit_kernel(const float* __restrict__ w1,
                              const float* __restrict__ w2,
                              const float* __restrict__ w3,
                              u16* __restrict__ Whi, u16* __restrict__ Wlo){
  const int tid = blockIdx.x * 256 + threadIdx.x;   // 0..106495
  const float* W; int K, off;
  if (tid < 8192)       { W = w1; K = 64;  off = 0; }
  else if (tid < 40960) { W = w2; K = 128; off = 8192; }
  else                  { W = w3; K = 256; off = 40960; }
  const int t      = tid - off;
  const int fragId = t >> 9;
  const int r      = t & 511;
  const int lane   = r >> 3, e = r & 7;
  const int KS     = K / 32;
  const int ks     = fragId % KS, mtg = fragId / KS;
  const int m      = mtg * 16 + (lane & 15);
  const int k      = ks * 32 + (lane >> 4) * 8 + e;
  const float v = W[(size_t)m * K + k];
  const u16 hi = f2bf(v);
  const u16 lo = f2bf(v - bf2f(hi));
  Whi[tid] = hi; Wlo[tid] = lo;
}

// ---- one MFMA layer: K -> M over 64 points; wave w owns m-quarter ----------
// MTW = M/64 m-tiles per wave; 4 A-tiles (16 pts each). Bias baked into acc.
template<int K, int M, int LDSKI, int LDSKO, bool WRITE>
__device__ __forceinline__ void mfma_layer(
    const u16* __restrict__ hin, u16* __restrict__ hout,
    const u16* __restrict__ Whi, const u16* __restrict__ Wlo,
    const float* __restrict__ bias, int w, int lane, f32x4 (*__restrict__ accRet)[4])
{
  constexpr int KS  = K / 32;
  constexpr int MTW = M / 64;
  const int lrow = lane & 15;   // A-row (pt in tile) == B/D col (m in tile)
  const int g    = lane >> 4;   // k-slice group / D row group

  f32x4 acc[4][MTW];
  #pragma unroll
  for (int mt = 0; mt < MTW; ++mt){
    const float bv = bias[(w * MTW + mt) * 16 + lrow];
    #pragma unroll
    for (int a = 0; a < 4; ++a){
      acc[a][mt][0] = bv; acc[a][mt][1] = bv; acc[a][mt][2] = bv; acc[a][mt][3] = bv;
    }
  }
  #pragma unroll
  for (int ks = 0; ks < KS; ++ks){
    const int eoff = ks * 32 + g * 8;
    short8 af[4];
    #pragma unroll
    for (int a = 0; a < 4; ++a)
      af[a] = *reinterpret_cast<const short8*>(hin + (a * 16 + lrow) * LDSKI + eoff);
    #pragma unroll
    for (int mt = 0; mt < MTW; ++mt){
      const int fragId = (w * MTW + mt) * KS + ks;
      const short8 bh = *reinterpret_cast<const short8*>(Whi + fragId * 512 + lane * 8);
      const short8 bl = *reinterpret_cast<const short8*>(Wlo + fragId * 512 + lane * 8);
      #pragma unroll
      for (int a = 0; a < 4; ++a)
        acc[a][mt] = __builtin_amdgcn_mfma_f32_16x16x32_bf16(af[a], bh, acc[a][mt], 0, 0, 0);
      #pragma unroll
      for (int a = 0; a < 4; ++a)
        acc[a][mt] = __builtin_amdgcn_mfma_f32_16x16x32_bf16(af[a], bl, acc[a][mt], 0, 0, 0);
    }
  }
  if constexpr (WRITE){
    #pragma unroll
    for (int a = 0; a < 4; ++a)
      #pragma unroll
      for (int mt = 0; mt < MTW; ++mt){
        const int m = (w * MTW + mt) * 16 + lrow;
        #pragma unroll
        for (int r = 0; r < 4; ++r){
          const int pt = a * 16 + g * 4 + r;      // D row = point
          hout[pt * LDSKO + m] = f2bf(lrelu(acc[a][mt][r]));
        }
      }
  } else {
    #pragma unroll
    for (int a = 0; a < 4; ++a)
      #pragma unroll
      for (int mt = 0; mt < MTW; ++mt)
        accRet[a][mt] = acc[a][mt];
  }
}

__global__ __launch_bounds__(256, 2)
void point_mfma_kernel(const float* __restrict__ points, const int* __restrict__ idx,
    const float* __restrict__ w0, const float* __restrict__ b0,
    const float* __restrict__ b1, const float* __restrict__ b2,
    const float* __restrict__ b3,
    const u16* __restrict__ Whi, const u16* __restrict__ Wlo,
    float* __restrict__ sums)
{
  __shared__ u16 h1[PTS][72];    // K=64  + 8 pad  ->  9216 B
  __shared__ u16 h2[PTS][136];   // K=128 + 8 pad -> 17408 B
  __shared__ u16 h3[PTS][264];   // K=256 + 8 pad -> 33792 B   (total 59 KB)

  const int t    = threadIdx.x;
  const int base = blockIdx.x * PTS;
  const int w    = t >> 6;
  const int lane = t & 63;

  // L0: 4 -> 64 fp32 straight from global (scalar-broadcast weights)
  {
    const int pt  = t & 63;
    const int grp = t >> 6;
    const float4 pv = *reinterpret_cast<const float4*>(points + (size_t)(base + pt) * 4);
    #pragma unroll
    for (int j = 0; j < 16; ++j){
      const int m = grp * 16 + j;
      const float4 wv = *reinterpret_cast<const float4*>(w0 + m * 4);
      const float s = b0[m] + pv.x * wv.x + pv.y * wv.y + pv.z * wv.z + pv.w * wv.w;
      h1[pt][m] = f2bf(lrelu(s));
    }
  }
  __syncthreads();
  mfma_layer< 64, 128,  72, 136, true >(&h1[0][0], &h2[0][0], Whi + 0,     Wlo + 0,     b1, w, lane, nullptr);
  __syncthreads();
  mfma_layer<128, 256, 136, 264, true >(&h2[0][0], &h3[0][0], Whi + 8192,  Wlo + 8192,  b2, w, lane, nullptr);
  __syncthreads();
  f32x4 acc3[4][4];
  mfma_layer<256, 256, 264,   1, false>(&h3[0][0], nullptr,   Whi + 40960, Wlo + 40960, b3, w, lane, acc3);

  // segment reduction (bias already baked per point)
  const int lrow = lane & 15;
  const int cF = find_cloud(idx, base);
  const int cL = find_cloud(idx, base + PTS - 1);
  if (cF == cL){
    #pragma unroll
    for (int mt = 0; mt < 4; ++mt){
      float s = 0.0f;
      #pragma unroll
      for (int a = 0; a < 4; ++a){
        const f32x4 v = acc3[a][mt];
        s += v[0] + v[1] + v[2] + v[3];
      }
      s += __shfl_xor(s, 16, 64);
      s += __shfl_xor(s, 32, 64);
      if (lane < 16)
        atomicAdd(sums + (size_t)cF * 256 + (w * 4 + mt) * 16 + lrow, s);
    }
  } else {
    const int g = lane >> 4;
    #pragma unroll
    for (int a = 0; a < 4; ++a)
      #pragma unroll
      for (int mt = 0; mt < 4; ++mt)
        #pragma unroll
        for (int r = 0; r < 4; ++r){
          const int pt = base + a * 16 + g * 4 + r;
          const int c  = find_cloud(idx, pt);
          atomicAdd(sums + (size_t)c * 256 + (w * 4 + mt) * 16 + lrow, acc3[a][mt][r]);
        }
  }
}

// ---- latent MLP: 4 clouds per block, 256 threads (thread = output dim) ----
__device__ __forceinline__ void lat_accum(const float (*__restrict__ in)[256],
    const float* __restrict__ W, const float* __restrict__ bias, int t, float acc[4])
{
  const float bv = bias[t];
  #pragma unroll
  for (int cl = 0; cl < 4; ++cl) acc[cl] = bv;
  const float4* __restrict__ wrow = reinterpret_cast<const float4*>(W + (size_t)t * 256);
  #pragma unroll 4
  for (int k4 = 0; k4 < 64; ++k4){
    const float4 w = wrow[k4];
    #pragma unroll
    for (int cl = 0; cl < 4; ++cl){
      const float4 a = *reinterpret_cast<const float4*>(&in[cl][k4 * 4]);
      acc[cl] += a.x * w.x + a.y * w.y + a.z * w.z + a.w * w.w;
    }
  }
}

__global__ __launch_bounds__(256)
void latent_kernel(const float* __restrict__ sums, const int* __restrict__ idx,
    const float* __restrict__ lw0, const float* __restrict__ lb0,
    const float* __restrict__ lw1, const float* __restrict__ lb1,
    const float* __restrict__ mw, const float* __restrict__ mb,
    const float* __restrict__ vw, const float* __restrict__ vb,
    float* __restrict__ out)
{
  __shared__ float s_in[4][256];
  __shared__ float s_a[4][256];
  const int t  = threadIdx.x;
  const int c0 = blockIdx.x * 4;

  #pragma unroll
  for (int cl = 0; cl < 4; ++cl){
    const int c = c0 + cl;
    const int cnt = idx[c] - (c ? idx[c - 1] : 0);
    s_in[cl][t] = sums[(size_t)c * 256 + t] / (float)cnt;
  }
  __syncthreads();

  float acc[4];
  lat_accum(s_in, lw0, lb0, t, acc);
  #pragma unroll
  for (int cl = 0; cl < 4; ++cl) s_a[cl][t] = lrelu(acc[cl]);
  __syncthreads();

  lat_accum(s_a, lw1, lb1, t, acc);
  __syncthreads();
  #pragma unroll
  for (int cl = 0; cl < 4; ++cl) s_in[cl][t] = lrelu(acc[cl]);
  __syncthreads();

  float accm[4], accv[4];
  lat_accum(s_in, mw, mb, t, accm);
  lat_accum(s_in, vw, vb, t, accv);
  #pragma unroll
  for (int cl = 0; cl < 4; ++cl){
    out[(size_t)(c0 + cl) * 256 + t]                    = accm[cl];  // mu
    out[(size_t)OUT_HALF + (size_t)(c0 + cl) * 256 + t] = accv[cl];  // log_var
  }
}

extern "C" void kernel_launch(void* const* d_in, const int* in_sizes, int n_in,
                              void* d_out, int out_size, void* d_ws, size_t ws_size,
                              hipStream_t stream) {
  const float* points = (const float*)d_in[0];
  const int*   idx    = (const int*)  d_in[1];
  const float* pw0 = (const float*)d_in[2],  *pb0 = (const float*)d_in[3];
  const float* pw1 = (const float*)d_in[4],  *pb1 = (const float*)d_in[5];
  const float* pw2 = (const float*)d_in[6],  *pb2 = (const float*)d_in[7];
  const float* pw3 = (const float*)d_in[8],  *pb3 = (const float*)d_in[9];
  const float* lw0 = (const float*)d_in[10], *lb0 = (const float*)d_in[11];
  const float* lw1 = (const float*)d_in[12], *lb1 = (const float*)d_in[13];
  const float* mw  = (const float*)d_in[14], *mb  = (const float*)d_in[15];
  const float* vw  = (const float*)d_in[16], *vb  = (const float*)d_in[17];
  float* out  = (float*)d_out;

  const size_t sums_bytes = (size_t)NB * 256 * sizeof(float);      // 4 MB
  const size_t wsplit_bytes = (size_t)WSPLIT_ELEMS * 2;            // 208 KB each
  float* sums; u16* Whi; u16* Wlo;
  if (ws_size >= sums_bytes + 2 * wsplit_bytes){
    sums = (float*)d_ws;
    Whi  = (u16*)((char*)d_ws + sums_bytes);
    Wlo  = Whi + WSPLIT_ELEMS;
  } else {
    // fallback: mu-half holds Wsplit (dead until latent writes mu at the end),
    // logvar-half holds sums (latent reads them just before writing log_var)
    Whi  = (u16*)d_out;
    Wlo  = Whi + WSPLIT_ELEMS;
    sums = out + OUT_HALF;
  }

  hipMemsetAsync(sums, 0, sums_bytes, stream);
  wsplit_kernel<<<WSPLIT_ELEMS / 256, 256, 0, stream>>>(pw1, pw2, pw3, Whi, Wlo);
  point_mfma_kernel<<<NTOT / PTS, 256, 0, stream>>>(points, idx,
      pw0, pb0, pb1, pb2, pb3, Whi, Wlo, sums);
  latent_kernel<<<NB / 4, 256, 0, stream>>>(sums, idx,
      lw0, lb0, lw1, lb1, mw, mb, vw, vb, out);
}

// Round 5
// 965.093 us; speedup vs baseline: 7.5412x; 1.2084x over previous
//
#include <hip/hip_runtime.h>

// Encoder: point MLP (4->64->128->256->256) via split-bf16 MFMA + segment-mean
// pool + fp32 latent MLP.
// Round 5: (1) LDS overlap h1/h3 -> 51.2 KB -> 3 blocks/CU (was 60.4 KB / 2);
//          (2) explicit 1-ks-ahead register double-buffer for A and B frags.
// Math identical to round 4 (passed, absmax 0):
// - Weights pre-split hi/lo bf16 (2 MFMAs per product), fragment-major.
// - A and B fragments use the SAME (lane,e)->k map, so k-order cancels.
// - C/D layout: col=lane&15, row=(lane>>4)*4+reg (HW-verified m89).

#define NB    4096
#define NTOT  1048576
#define PTS   64
#define OUT_HALF (NB * 256)       // 1048576 floats
#define WSPLIT_ELEMS 106496       // 8192 + 32768 + 65536 frag-elems per array

typedef __attribute__((ext_vector_type(8))) short short8;
typedef __attribute__((ext_vector_type(4))) float f32x4;
typedef unsigned short u16;
typedef unsigned int   u32;

__device__ __forceinline__ float lrelu(float x){ return x > 0.0f ? x : 0.01f * x; }

__device__ __forceinline__ u16 f2bf(float x){            // round-to-nearest-even
  union{float f; u32 u;} v; v.f = x;
  u32 r = v.u + 0x7fffu + ((v.u >> 16) & 1u);
  return (u16)(r >> 16);
}
__device__ __forceinline__ float bf2f(u16 h){
  union{u32 u; float f;} v; v.u = ((u32)h) << 16; return v.f;
}

__device__ __forceinline__ int find_cloud(const int* __restrict__ idx, int j){
  int lo = 0, hi = NB;
  while (lo < hi){
    int mid = (lo + hi) >> 1;
    if (idx[mid] <= j) lo = mid + 1; else hi = mid;
  }
  return lo;
}

// ---- prologue: split W into hi/lo bf16, fragment-major ---------------------
// frag = 512 elems: [lane 0..63][e 0..7]; elem (lane,e) = W[mtg*16+(lane&15)]
// [ks*32+(lane>>4)*8+e]. Layer offsets (u16 elems): L1=0, L2=8192, L3=40960.
__global__ void wsplit_kernel(const float* __restrict__ w1,
                              const float* __restrict__ w2,
                              const float* __restrict__ w3,
                              u16* __restrict__ Whi, u16* __restrict__ Wlo){
  const int tid = blockIdx.x * 256 + threadIdx.x;   // 0..106495
  const float* W; int K, off;
  if (tid < 8192)       { W = w1; K = 64;  off = 0; }
  else if (tid < 40960) { W = w2; K = 128; off = 8192; }
  else                  { W = w3; K = 256; off = 40960; }
  const int t      = tid - off;
  const int fragId = t >> 9;
  const int r      = t & 511;
  const int lane   = r >> 3, e = r & 7;
  const int KS     = K / 32;
  const int ks     = fragId % KS, mtg = fragId / KS;
  const int m      = mtg * 16 + (lane & 15);
  const int k      = ks * 32 + (lane >> 4) * 8 + e;
  const float v = W[(size_t)m * K + k];
  const u16 hi = f2bf(v);
  const u16 lo = f2bf(v - bf2f(hi));
  Whi[tid] = hi; Wlo[tid] = lo;
}

// ---- one MFMA layer: K -> M over 64 points; wave w owns m-quarter ----------
// MTW = M/64 m-tiles per wave; 4 A-tiles (16 pts each). Bias baked into acc.
// Explicit 1-ks-ahead register double-buffer for A (LDS) and B (global) frags.
template<int K, int M, int LDSKI, int LDSKO, bool WRITE>
__device__ __forceinline__ void mfma_layer(
    const u16* __restrict__ hin, u16* __restrict__ hout,
    const u16* __restrict__ Whi, const u16* __restrict__ Wlo,
    const float* __restrict__ bias, int w, int lane, f32x4 (*__restrict__ accRet)[4])
{
  constexpr int KS  = K / 32;
  constexpr int MTW = M / 64;
  const int lrow = lane & 15;   // A-row (pt in tile) == B/D col (m in tile)
  const int g    = lane >> 4;   // k-slice group / D row group

  f32x4 acc[4][MTW];
  #pragma unroll
  for (int mt = 0; mt < MTW; ++mt){
    const float bv = bias[(w * MTW + mt) * 16 + lrow];
    #pragma unroll
    for (int a = 0; a < 4; ++a){
      acc[a][mt][0] = bv; acc[a][mt][1] = bv; acc[a][mt][2] = bv; acc[a][mt][3] = bv;
    }
  }

  // fragment (mt, ks) lives at (mt*KS + ks)*512 + lane*8 past these bases
  const u16* __restrict__ bptr = Whi + (size_t)(w * MTW) * KS * 512 + lane * 8;
  const u16* __restrict__ lptr = Wlo + (size_t)(w * MTW) * KS * 512 + lane * 8;

  short8 af[4], bh[MTW], bl[MTW];
  #pragma unroll
  for (int a = 0; a < 4; ++a)
    af[a] = *reinterpret_cast<const short8*>(hin + (a * 16 + lrow) * LDSKI + g * 8);
  #pragma unroll
  for (int mt = 0; mt < MTW; ++mt){
    bh[mt] = *reinterpret_cast<const short8*>(bptr + (size_t)mt * KS * 512);
    bl[mt] = *reinterpret_cast<const short8*>(lptr + (size_t)mt * KS * 512);
  }

  #pragma unroll
  for (int ks = 0; ks < KS; ++ks){
    short8 af2[4], bh2[MTW], bl2[MTW];
    if (ks + 1 < KS){                                  // compile-time folded
      const int eoff2 = (ks + 1) * 32 + g * 8;
      #pragma unroll
      for (int a = 0; a < 4; ++a)
        af2[a] = *reinterpret_cast<const short8*>(hin + (a * 16 + lrow) * LDSKI + eoff2);
      #pragma unroll
      for (int mt = 0; mt < MTW; ++mt){
        bh2[mt] = *reinterpret_cast<const short8*>(bptr + (size_t)(mt * KS + ks + 1) * 512);
        bl2[mt] = *reinterpret_cast<const short8*>(lptr + (size_t)(mt * KS + ks + 1) * 512);
      }
    }
    #pragma unroll
    for (int mt = 0; mt < MTW; ++mt){
      #pragma unroll
      for (int a = 0; a < 4; ++a)
        acc[a][mt] = __builtin_amdgcn_mfma_f32_16x16x32_bf16(af[a], bh[mt], acc[a][mt], 0, 0, 0);
      #pragma unroll
      for (int a = 0; a < 4; ++a)
        acc[a][mt] = __builtin_amdgcn_mfma_f32_16x16x32_bf16(af[a], bl[mt], acc[a][mt], 0, 0, 0);
    }
    if (ks + 1 < KS){
      #pragma unroll
      for (int a = 0; a < 4; ++a) af[a] = af2[a];
      #pragma unroll
      for (int mt = 0; mt < MTW; ++mt){ bh[mt] = bh2[mt]; bl[mt] = bl2[mt]; }
    }
  }

  if constexpr (WRITE){
    #pragma unroll
    for (int a = 0; a < 4; ++a)
      #pragma unroll
      for (int mt = 0; mt < MTW; ++mt){
        const int m = (w * MTW + mt) * 16 + lrow;
        #pragma unroll
        for (int r = 0; r < 4; ++r){
          const int pt = a * 16 + g * 4 + r;      // D row = point
          hout[pt * LDSKO + m] = f2bf(lrelu(acc[a][mt][r]));
        }
      }
  } else {
    #pragma unroll
    for (int a = 0; a < 4; ++a)
      #pragma unroll
      for (int mt = 0; mt < MTW; ++mt)
        accRet[a][mt] = acc[a][mt];
  }
}

__global__ __launch_bounds__(256, 3)
void point_mfma_kernel(const float* __restrict__ points, const int* __restrict__ idx,
    const float* __restrict__ w0, const float* __restrict__ b0,
    const float* __restrict__ b1, const float* __restrict__ b2,
    const float* __restrict__ b3,
    const u16* __restrict__ Whi, const u16* __restrict__ Wlo,
    float* __restrict__ sums)
{
  // Overlapped LDS arena (51200 B -> 3 blocks/CU):
  //   h2 @ 0      (17408 B)   live: L1-write .. L2-read
  //   h1 @ 17408  ( 9216 B)   live: L0-write .. L1-read
  //   h3 @ 17408  (33792 B)   live: L2-write .. L3-read (h1 dead by then)
  __shared__ __align__(16) char smem[51200];
  u16 (*h2)[136] = reinterpret_cast<u16(*)[136]>(smem);
  u16 (*h1)[72]  = reinterpret_cast<u16(*)[72]>(smem + 17408);
  u16 (*h3)[264] = reinterpret_cast<u16(*)[264]>(smem + 17408);

  const int t    = threadIdx.x;
  const int base = blockIdx.x * PTS;
  const int w    = t >> 6;
  const int lane = t & 63;

  // L0: 4 -> 64 fp32 straight from global (scalar-broadcast weights)
  {
    const int pt  = t & 63;
    const int grp = t >> 6;
    const float4 pv = *reinterpret_cast<const float4*>(points + (size_t)(base + pt) * 4);
    #pragma unroll
    for (int j = 0; j < 16; ++j){
      const int m = grp * 16 + j;
      const float4 wv = *reinterpret_cast<const float4*>(w0 + m * 4);
      const float s = b0[m] + pv.x * wv.x + pv.y * wv.y + pv.z * wv.z + pv.w * wv.w;
      h1[pt][m] = f2bf(lrelu(s));
    }
  }
  __syncthreads();
  mfma_layer< 64, 128,  72, 136, true >(&h1[0][0], &h2[0][0], Whi + 0,     Wlo + 0,     b1, w, lane, nullptr);
  __syncthreads();
  mfma_layer<128, 256, 136, 264, true >(&h2[0][0], &h3[0][0], Whi + 8192,  Wlo + 8192,  b2, w, lane, nullptr);
  __syncthreads();
  f32x4 acc3[4][4];
  mfma_layer<256, 256, 264,   1, false>(&h3[0][0], nullptr,   Whi + 40960, Wlo + 40960, b3, w, lane, acc3);

  // segment reduction (bias already baked per point)
  const int lrow = lane & 15;
  const int cF = find_cloud(idx, base);
  const int cL = find_cloud(idx, base + PTS - 1);
  if (cF == cL){
    #pragma unroll
    for (int mt = 0; mt < 4; ++mt){
      float s = 0.0f;
      #pragma unroll
      for (int a = 0; a < 4; ++a){
        const f32x4 v = acc3[a][mt];
        s += v[0] + v[1] + v[2] + v[3];
      }
      s += __shfl_xor(s, 16, 64);
      s += __shfl_xor(s, 32, 64);
      if (lane < 16)
        atomicAdd(sums + (size_t)cF * 256 + (w * 4 + mt) * 16 + lrow, s);
    }
  } else {
    const int g = lane >> 4;
    #pragma unroll
    for (int a = 0; a < 4; ++a)
      #pragma unroll
      for (int mt = 0; mt < 4; ++mt)
        #pragma unroll
        for (int r = 0; r < 4; ++r){
          const int pt = base + a * 16 + g * 4 + r;
          const int c  = find_cloud(idx, pt);
          atomicAdd(sums + (size_t)c * 256 + (w * 4 + mt) * 16 + lrow, acc3[a][mt][r]);
        }
  }
}

// ---- latent MLP: 4 clouds per block, 256 threads (thread = output dim) ----
__device__ __forceinline__ void lat_accum(const float (*__restrict__ in)[256],
    const float* __restrict__ W, const float* __restrict__ bias, int t, float acc[4])
{
  const float bv = bias[t];
  #pragma unroll
  for (int cl = 0; cl < 4; ++cl) acc[cl] = bv;
  const float4* __restrict__ wrow = reinterpret_cast<const float4*>(W + (size_t)t * 256);
  #pragma unroll 4
  for (int k4 = 0; k4 < 64; ++k4){
    const float4 w = wrow[k4];
    #pragma unroll
    for (int cl = 0; cl < 4; ++cl){
      const float4 a = *reinterpret_cast<const float4*>(&in[cl][k4 * 4]);
      acc[cl] += a.x * w.x + a.y * w.y + a.z * w.z + a.w * w.w;
    }
  }
}

__global__ __launch_bounds__(256)
void latent_kernel(const float* __restrict__ sums, const int* __restrict__ idx,
    const float* __restrict__ lw0, const float* __restrict__ lb0,
    const float* __restrict__ lw1, const float* __restrict__ lb1,
    const float* __restrict__ mw, const float* __restrict__ mb,
    const float* __restrict__ vw, const float* __restrict__ vb,
    float* __restrict__ out)
{
  __shared__ float s_in[4][256];
  __shared__ float s_a[4][256];
  const int t  = threadIdx.x;
  const int c0 = blockIdx.x * 4;

  #pragma unroll
  for (int cl = 0; cl < 4; ++cl){
    const int c = c0 + cl;
    const int cnt = idx[c] - (c ? idx[c - 1] : 0);
    s_in[cl][t] = sums[(size_t)c * 256 + t] / (float)cnt;
  }
  __syncthreads();

  float acc[4];
  lat_accum(s_in, lw0, lb0, t, acc);
  #pragma unroll
  for (int cl = 0; cl < 4; ++cl) s_a[cl][t] = lrelu(acc[cl]);
  __syncthreads();

  lat_accum(s_a, lw1, lb1, t, acc);
  __syncthreads();
  #pragma unroll
  for (int cl = 0; cl < 4; ++cl) s_in[cl][t] = lrelu(acc[cl]);
  __syncthreads();

  float accm[4], accv[4];
  lat_accum(s_in, mw, mb, t, accm);
  lat_accum(s_in, vw, vb, t, accv);
  #pragma unroll
  for (int cl = 0; cl < 4; ++cl){
    out[(size_t)(c0 + cl) * 256 + t]                    = accm[cl];  // mu
    out[(size_t)OUT_HALF + (size_t)(c0 + cl) * 256 + t] = accv[cl];  // log_var
  }
}

extern "C" void kernel_launch(void* const* d_in, const int* in_sizes, int n_in,
                              void* d_out, int out_size, void* d_ws, size_t ws_size,
                              hipStream_t stream) {
  const float* points = (const float*)d_in[0];
  const int*   idx    = (const int*)  d_in[1];
  const float* pw0 = (const float*)d_in[2],  *pb0 = (const float*)d_in[3];
  const float* pw1 = (const float*)d_in[4],  *pb1 = (const float*)d_in[5];
  const float* pw2 = (const float*)d_in[6],  *pb2 = (const float*)d_in[7];
  const float* pw3 = (const float*)d_in[8],  *pb3 = (const float*)d_in[9];
  const float* lw0 = (const float*)d_in[10], *lb0 = (const float*)d_in[11];
  const float* lw1 = (const float*)d_in[12], *lb1 = (const float*)d_in[13];
  const float* mw  = (const float*)d_in[14], *mb  = (const float*)d_in[15];
  const float* vw  = (const float*)d_in[16], *vb  = (const float*)d_in[17];
  float* out  = (float*)d_out;

  const size_t sums_bytes = (size_t)NB * 256 * sizeof(float);      // 4 MB
  const size_t wsplit_bytes = (size_t)WSPLIT_ELEMS * 2;            // 208 KB each
  float* sums; u16* Whi; u16* Wlo;
  if (ws_size >= sums_bytes + 2 * wsplit_bytes){
    sums = (float*)d_ws;
    Whi  = (u16*)((char*)d_ws + sums_bytes);
    Wlo  = Whi + WSPLIT_ELEMS;
  } else {
    // fallback: mu-half holds Wsplit (dead until latent writes mu at the end),
    // logvar-half holds sums (latent reads them just before writing log_var)
    Whi  = (u16*)d_out;
    Wlo  = Whi + WSPLIT_ELEMS;
    sums = out + OUT_HALF;
  }

  hipMemsetAsync(sums, 0, sums_bytes, stream);
  wsplit_kernel<<<WSPLIT_ELEMS / 256, 256, 0, stream>>>(pw1, pw2, pw3, Whi, Wlo);
  point_mfma_kernel<<<NTOT / PTS, 256, 0, stream>>>(points, idx,
      pw0, pb0, pb1, pb2, pb3, Whi, Wlo, sums);
  latent_kernel<<<NB / 4, 256, 0, stream>>>(sums, idx,
      lw0, lb0, lw1, lb1, mw, mb, vw, vb, out);
}